// Round 5
// baseline (952.663 us; speedup 1.0000x reference)
//
#include <hip/hip_runtime.h>

#define NN 100000   // nodes
#define NE 3200000  // edges
#define NF 512      // in features
#define NH 16       // hidden
#define NC 7        // classes

#define BUCKSZ 64
#define NBUCK 1563          // ceil(NN/64); bucket = dst >> 6
#define ASTEP 512           // bucket edge lists padded to multiple of 512
#define NEPAD (NE + NBUCK * ASTEP)   // 4,000,256
#define PADVAL NN           // pad payload: li=0, src=NN (zeroed pad row)
#define PBLK 128            // partition blocks

// ---------------------------------------------------------------------------
// Packed butterfly reduction: acc[16] -> every lane holds full sum of col
// (lane&15).  17 shuffles.
// ---------------------------------------------------------------------------
__device__ __forceinline__ float reduce16(const float acc[16], int lane) {
  float w8[8];
#pragma unroll
  for (int i = 0; i < 8; ++i) {
    float sel = (lane & 1) ? acc[2 * i + 1] : acc[2 * i];
    float oth = (lane & 1) ? acc[2 * i]     : acc[2 * i + 1];
    w8[i] = sel + __shfl_xor(oth, 1);
  }
  float w4[4];
#pragma unroll
  for (int i = 0; i < 4; ++i) {
    float sel = (lane & 2) ? w8[2 * i + 1] : w8[2 * i];
    float oth = (lane & 2) ? w8[2 * i]     : w8[2 * i + 1];
    w4[i] = sel + __shfl_xor(oth, 2);
  }
  float w2[2];
#pragma unroll
  for (int i = 0; i < 2; ++i) {
    float sel = (lane & 4) ? w4[2 * i + 1] : w4[2 * i];
    float oth = (lane & 4) ? w4[2 * i]     : w4[2 * i + 1];
    w2[i] = sel + __shfl_xor(oth, 4);
  }
  float sel = (lane & 8) ? w2[1] : w2[0];
  float oth = (lane & 8) ? w2[0] : w2[1];
  float v = sel + __shfl_xor(oth, 8);
  v += __shfl_xor(v, 16);
  v += __shfl_xor(v, 32);
  return v;
}

// ---------------------------------------------------------------------------
// GEMM1: h0 = x @ W1.  One wave per 2 rows, W1 in 128 VGPRs/lane.
// ---------------------------------------------------------------------------
__global__ __launch_bounds__(256) void gemm1_kernel(const float* __restrict__ x,
                                                    const float* __restrict__ W1,
                                                    float* __restrict__ h0) {
  const int lane = threadIdx.x & 63;
  const int wave = (blockIdx.x * blockDim.x + threadIdx.x) >> 6;
  const int nw   = (gridDim.x * blockDim.x) >> 6;

  float w[8][NH];
#pragma unroll
  for (int i = 0; i < 4; ++i)
#pragma unroll
    for (int j = 0; j < NH; ++j) {
      w[i][j]     = W1[(4 * lane + i) * NH + j];
      w[4 + i][j] = W1[(256 + 4 * lane + i) * NH + j];
    }

  for (int pr = wave; pr < NN / 2; pr += nw) {
    int r0 = 2 * pr;
    const float4* x0 = (const float4*)(x + (size_t)r0 * NF);
    const float4* x1 = (const float4*)(x + (size_t)(r0 + 1) * NF);
    float4 a0 = x0[lane], b0 = x0[64 + lane];
    float4 a1 = x1[lane], b1 = x1[64 + lane];
    float A0[8] = {a0.x, a0.y, a0.z, a0.w, b0.x, b0.y, b0.z, b0.w};
    float A1[8] = {a1.x, a1.y, a1.z, a1.w, b1.x, b1.y, b1.z, b1.w};
    float c0[NH], c1[NH];
#pragma unroll
    for (int j = 0; j < NH; ++j) { c0[j] = 0.f; c1[j] = 0.f; }
#pragma unroll
    for (int i = 0; i < 8; ++i)
#pragma unroll
      for (int j = 0; j < NH; ++j) {
        c0[j] += A0[i] * w[i][j];
        c1[j] += A1[i] * w[i][j];
      }
    float v0 = reduce16(c0, lane);
    float v1 = reduce16(c1, lane);
    if (lane < 16)      h0[(size_t)r0 * NH + lane] = v0;
    else if (lane < 32) h0[(size_t)(r0 + 1) * NH + (lane & 15)] = v1;
  }
}

// ---------------------------------------------------------------------------
// ebuf prefill with pad payload.
// ---------------------------------------------------------------------------
__global__ __launch_bounds__(256) void prefill_kernel(int4* __restrict__ ebuf4) {
  int i = blockIdx.x * blockDim.x + threadIdx.x;
  if (i < NEPAD / 4) ebuf4[i] = make_int4(PADVAL, PADVAL, PADVAL, PADVAL);
}

// ---------------------------------------------------------------------------
// Bucket histogram, int4-vectorized grid-stride.
// ---------------------------------------------------------------------------
__global__ __launch_bounds__(256) void bucket_hist_kernel(const int* __restrict__ ei,
                                                          int* __restrict__ gcount) {
  __shared__ int hist[NBUCK];
  for (int i = threadIdx.x; i < NBUCK; i += 256) hist[i] = 0;
  __syncthreads();
  const int4* d4 = (const int4*)(ei + NE);
  int stride = gridDim.x * 256;
  for (int i = blockIdx.x * 256 + threadIdx.x; i < NE / 4; i += stride) {
    int4 v = d4[i];
    atomicAdd(&hist[v.x >> 6], 1);
    atomicAdd(&hist[v.y >> 6], 1);
    atomicAdd(&hist[v.z >> 6], 1);
    atomicAdd(&hist[v.w >> 6], 1);
  }
  __syncthreads();
  for (int i = threadIdx.x; i < NBUCK; i += 256) {
    int c = hist[i];
    if (c) atomicAdd(&gcount[i], c);
  }
}

// ---------------------------------------------------------------------------
// Exclusive scan of PADDED bucket counts (single block, 1024 thr, 2/thread).
// gbase[b] = padded exclusive prefix; gbase[NBUCK] = padded total.
// ---------------------------------------------------------------------------
__global__ __launch_bounds__(1024) void bucket_scan_kernel(const int* __restrict__ gcount,
                                                           int* __restrict__ gbase,
                                                           int* __restrict__ gcursor) {
  __shared__ int s[1024];
  int t = threadIdx.x;
  int i0 = 2 * t, i1 = 2 * t + 1;
  int a0 = (i0 < NBUCK) ? ((gcount[i0] + ASTEP - 1) / ASTEP) * ASTEP : 0;
  int a1 = (i1 < NBUCK) ? ((gcount[i1] + ASTEP - 1) / ASTEP) * ASTEP : 0;
  s[t] = a0 + a1;
  __syncthreads();
  for (int off = 1; off < 1024; off <<= 1) {
    int v = (t >= off) ? s[t - off] : 0;
    __syncthreads();
    s[t] += v;
    __syncthreads();
  }
  int exclPair = s[t] - (a0 + a1);
  if (i0 < NBUCK) { gbase[i0] = exclPair;      gcursor[i0] = exclPair; }
  if (i1 < NBUCK) { gbase[i1] = exclPair + a0; gcursor[i1] = exclPair + a0; }
  if (t == 1023) gbase[NBUCK] = s[1023];
}

// ---------------------------------------------------------------------------
// Partition: chunked multi-split.  Payload: (local_dst << 17) | src.
// Pad tail of each bucket keeps the prefect pad payload.
// ---------------------------------------------------------------------------
__global__ __launch_bounds__(256) void partition_kernel(const int* __restrict__ ei,
                                                        int* __restrict__ gcursor,
                                                        int* __restrict__ ebuf) {
  __shared__ int hist[NBUCK];
  __shared__ int cbase[NBUCK];
  for (int i = threadIdx.x; i < NBUCK; i += 256) hist[i] = 0;
  __syncthreads();
  const int4* d4 = (const int4*)(ei + NE);
  const int4* s4 = (const int4*)ei;
  int stride = gridDim.x * 256;
  for (int i = blockIdx.x * 256 + threadIdx.x; i < NE / 4; i += stride) {
    int4 v = d4[i];
    atomicAdd(&hist[v.x >> 6], 1);
    atomicAdd(&hist[v.y >> 6], 1);
    atomicAdd(&hist[v.z >> 6], 1);
    atomicAdd(&hist[v.w >> 6], 1);
  }
  __syncthreads();
  for (int i = threadIdx.x; i < NBUCK; i += 256) {
    int c = hist[i];
    cbase[i] = c ? atomicAdd(&gcursor[i], c) : 0;
  }
  __syncthreads();
  for (int i = threadIdx.x; i < NBUCK; i += 256) hist[i] = 0;
  __syncthreads();
  for (int i = blockIdx.x * 256 + threadIdx.x; i < NE / 4; i += stride) {
    int4 d = d4[i];
    int4 s = s4[i];
    int b0 = d.x >> 6, b1 = d.y >> 6, b2 = d.z >> 6, b3 = d.w >> 6;
    int o0 = atomicAdd(&hist[b0], 1);
    int o1 = atomicAdd(&hist[b1], 1);
    int o2 = atomicAdd(&hist[b2], 1);
    int o3 = atomicAdd(&hist[b3], 1);
    ebuf[cbase[b0] + o0] = ((d.x & 63) << 17) | s.x;
    ebuf[cbase[b1] + o1] = ((d.y & 63) << 17) | s.y;
    ebuf[cbase[b2] + o2] = ((d.z & 63) << 17) | s.z;
    ebuf[cbase[b3] + o3] = ((d.w & 63) << 17) | s.w;
  }
}

// ---------------------------------------------------------------------------
// Layer-1 aggregate + relu + bias + W2.  One block per 64-node bucket.
// 4 lanes/edge (float4), 512 edges/iter, 8 batched gathers/thread, NO
// conditionals in the loop (pad edges read zeroed h0 row NN).
// LDS acc 64 x 17.
// ---------------------------------------------------------------------------
__global__ __launch_bounds__(256) void agg1_kernel(const int* __restrict__ gbase,
                                                   const int* __restrict__ ebuf,
                                                   const float* __restrict__ h0,
                                                   const float* __restrict__ b1,
                                                   const float* __restrict__ W2,
                                                   float* __restrict__ p) {
  __shared__ float acc[BUCKSZ * 17];
  for (int i = threadIdx.x; i < BUCKSZ * 17; i += 256) acc[i] = 0.f;
  __syncthreads();
  int b = blockIdx.x;
  int start = gbase[b];
  int nIter = (gbase[b + 1] - start) >> 9;
  int eg = threadIdx.x >> 2, c = threadIdx.x & 3;
  const float* hc = h0 + 4 * c;
  for (int it = 0; it < nIter; ++it) {
    int e = start + it * 512 + eg;
    int pk[8];
#pragma unroll
    for (int u = 0; u < 8; ++u) pk[u] = ebuf[e + (u << 6)];
    float4 hv[8];
#pragma unroll
    for (int u = 0; u < 8; ++u)
      hv[u] = *(const float4*)(hc + (size_t)(pk[u] & 0x1FFFF) * NH);
#pragma unroll
    for (int u = 0; u < 8; ++u) {
      float* a = &acc[(pk[u] >> 17) * 17 + 4 * c];
      atomicAdd(a + 0, hv[u].x);
      atomicAdd(a + 1, hv[u].y);
      atomicAdd(a + 2, hv[u].z);
      atomicAdd(a + 3, hv[u].w);
    }
  }
  __syncthreads();
  int li = threadIdx.x;
  if (li < BUCKSZ) {
    int node = b * BUCKSZ + li;
    if (node < NN) {
      float h[NH];
#pragma unroll
      for (int k = 0; k < NH; ++k) h[k] = fmaxf(acc[li * 17 + k] + b1[k], 0.f);
      float o[8];
#pragma unroll
      for (int j = 0; j < NC; ++j) {
        float s = 0.f;
#pragma unroll
        for (int k = 0; k < NH; ++k) s += h[k] * W2[k * NC + j];
        o[j] = s;
      }
      o[7] = 0.f;
      float4* pr = (float4*)(p + (size_t)node * 8);
      pr[0] = make_float4(o[0], o[1], o[2], o[3]);
      pr[1] = make_float4(o[4], o[5], o[6], o[7]);
    }
  }
}

// ---------------------------------------------------------------------------
// Layer-2 aggregate + bias + log_softmax.  4 lanes/edge (float2),
// 512 edges/iter, 8 batched gathers, no conditionals.  LDS acc 64 x 9.
// ---------------------------------------------------------------------------
__global__ __launch_bounds__(256) void agg2_kernel(const int* __restrict__ gbase,
                                                   const int* __restrict__ ebuf,
                                                   const float* __restrict__ p,
                                                   const float* __restrict__ b2,
                                                   float* __restrict__ out) {
  __shared__ float acc[BUCKSZ * 9];
  for (int i = threadIdx.x; i < BUCKSZ * 9; i += 256) acc[i] = 0.f;
  __syncthreads();
  int b = blockIdx.x;
  int start = gbase[b];
  int nIter = (gbase[b + 1] - start) >> 9;
  int eg = threadIdx.x >> 2, c = threadIdx.x & 3;
  const float* pc = p + 2 * c;
  for (int it = 0; it < nIter; ++it) {
    int e = start + it * 512 + eg;
    int pk[8];
#pragma unroll
    for (int u = 0; u < 8; ++u) pk[u] = ebuf[e + (u << 6)];
    float2 pv[8];
#pragma unroll
    for (int u = 0; u < 8; ++u)
      pv[u] = *(const float2*)(pc + (size_t)(pk[u] & 0x1FFFF) * 8);
#pragma unroll
    for (int u = 0; u < 8; ++u) {
      float* a = &acc[(pk[u] >> 17) * 9 + 2 * c];
      atomicAdd(a + 0, pv[u].x);
      atomicAdd(a + 1, pv[u].y);
    }
  }
  __syncthreads();
  int li = threadIdx.x;
  if (li < BUCKSZ) {
    int node = b * BUCKSZ + li;
    if (node < NN) {
      float z[NC];
      float m = -1e30f;
#pragma unroll
      for (int j = 0; j < NC; ++j) {
        z[j] = acc[li * 9 + j] + b2[j];
        m = fmaxf(m, z[j]);
      }
      float s = 0.f;
#pragma unroll
      for (int j = 0; j < NC; ++j) s += __expf(z[j] - m);
      float l = __logf(s);
#pragma unroll
      for (int j = 0; j < NC; ++j) out[(size_t)node * NC + j] = z[j] - m - l;
    }
  }
}

extern "C" void kernel_launch(void* const* d_in, const int* in_sizes, int n_in,
                              void* d_out, int out_size, void* d_ws, size_t ws_size,
                              hipStream_t stream) {
  const float* x  = (const float*)d_in[0];
  const int*   ei = (const int*)d_in[1];
  const float* W1 = (const float*)d_in[2];
  const float* b1 = (const float*)d_in[3];
  const float* W2 = (const float*)d_in[4];
  const float* b2 = (const float*)d_in[5];
  float* out = (float*)d_out;

  // ws layout (~25.7 MB); h0 and p carry one extra ZERO pad row (index NN).
  float* h0      = (float*)d_ws;                        // (NN+1)*16
  float* p       = h0 + (size_t)(NN + 1) * NH;          // (NN+1)*8
  int*   ebuf    = (int*)(p + (size_t)(NN + 1) * 8);    // NEPAD
  int*   gcount  = ebuf + NEPAD;                        // NBUCK
  int*   gbase   = gcount + NBUCK;                      // NBUCK+1
  int*   gcursor = gbase + NBUCK + 1;                   // NBUCK

  hipMemsetAsync(gcount, 0, NBUCK * sizeof(int), stream);
  hipMemsetAsync(h0 + (size_t)NN * NH, 0, NH * sizeof(float), stream);
  hipMemsetAsync(p + (size_t)NN * 8, 0, 8 * sizeof(float), stream);

  prefill_kernel<<<(NEPAD / 4 + 255) / 256, 256, 0, stream>>>((int4*)ebuf);
  bucket_hist_kernel<<<256, 256, 0, stream>>>(ei, gcount);
  bucket_scan_kernel<<<1, 1024, 0, stream>>>(gcount, gbase, gcursor);
  partition_kernel<<<PBLK, 256, 0, stream>>>(ei, gcursor, ebuf);
  gemm1_kernel<<<2048, 256, 0, stream>>>(x, W1, h0);
  agg1_kernel<<<NBUCK, 256, 0, stream>>>(gbase, ebuf, h0, b1, W2, p);
  agg2_kernel<<<NBUCK, 256, 0, stream>>>(gbase, ebuf, p, b2, out);
}

// Round 6
// 952.237 us; speedup vs baseline: 1.0004x; 1.0004x over previous
//
#include <hip/hip_runtime.h>

#define NN 100000   // nodes
#define NE 3200000  // edges
#define NF 512      // in features
#define NH 16       // hidden
#define NC 7        // classes

#define BUCKSZ 64
#define NBUCK 1563          // ceil(NN/64); bucket = dst >> 6
#define ASTEP 512           // bucket edge lists padded to multiple of 512
#define NEPAD (NE + NBUCK * ASTEP)   // 4,000,256
#define PADVAL NN           // pad payload: li=0, src=NN (zeroed pad row)
#define PBLK 128            // partition blocks

#define SBAR() __builtin_amdgcn_sched_barrier(0)

// ---------------------------------------------------------------------------
// Packed butterfly reduction: acc[16] -> every lane holds full sum of col
// (lane&15).  17 shuffles.
// ---------------------------------------------------------------------------
__device__ __forceinline__ float reduce16(const float acc[16], int lane) {
  float w8[8];
#pragma unroll
  for (int i = 0; i < 8; ++i) {
    float sel = (lane & 1) ? acc[2 * i + 1] : acc[2 * i];
    float oth = (lane & 1) ? acc[2 * i]     : acc[2 * i + 1];
    w8[i] = sel + __shfl_xor(oth, 1);
  }
  float w4[4];
#pragma unroll
  for (int i = 0; i < 4; ++i) {
    float sel = (lane & 2) ? w8[2 * i + 1] : w8[2 * i];
    float oth = (lane & 2) ? w8[2 * i]     : w8[2 * i + 1];
    w4[i] = sel + __shfl_xor(oth, 2);
  }
  float w2[2];
#pragma unroll
  for (int i = 0; i < 2; ++i) {
    float sel = (lane & 4) ? w4[2 * i + 1] : w4[2 * i];
    float oth = (lane & 4) ? w4[2 * i]     : w4[2 * i + 1];
    w2[i] = sel + __shfl_xor(oth, 4);
  }
  float sel = (lane & 8) ? w2[1] : w2[0];
  float oth = (lane & 8) ? w2[0] : w2[1];
  float v = sel + __shfl_xor(oth, 8);
  v += __shfl_xor(v, 16);
  v += __shfl_xor(v, 32);
  return v;
}

// ---------------------------------------------------------------------------
// GEMM1: h0 = x @ W1.  One wave per 2 rows, W1 in 128 VGPRs/lane.
// ---------------------------------------------------------------------------
__global__ __launch_bounds__(256) void gemm1_kernel(const float* __restrict__ x,
                                                    const float* __restrict__ W1,
                                                    float* __restrict__ h0) {
  const int lane = threadIdx.x & 63;
  const int wave = (blockIdx.x * blockDim.x + threadIdx.x) >> 6;
  const int nw   = (gridDim.x * blockDim.x) >> 6;

  float w[8][NH];
#pragma unroll
  for (int i = 0; i < 4; ++i)
#pragma unroll
    for (int j = 0; j < NH; ++j) {
      w[i][j]     = W1[(4 * lane + i) * NH + j];
      w[4 + i][j] = W1[(256 + 4 * lane + i) * NH + j];
    }

  for (int pr = wave; pr < NN / 2; pr += nw) {
    int r0 = 2 * pr;
    const float4* x0 = (const float4*)(x + (size_t)r0 * NF);
    const float4* x1 = (const float4*)(x + (size_t)(r0 + 1) * NF);
    float4 a0 = x0[lane], b0 = x0[64 + lane];
    float4 a1 = x1[lane], b1 = x1[64 + lane];
    float A0[8] = {a0.x, a0.y, a0.z, a0.w, b0.x, b0.y, b0.z, b0.w};
    float A1[8] = {a1.x, a1.y, a1.z, a1.w, b1.x, b1.y, b1.z, b1.w};
    float c0[NH], c1[NH];
#pragma unroll
    for (int j = 0; j < NH; ++j) { c0[j] = 0.f; c1[j] = 0.f; }
#pragma unroll
    for (int i = 0; i < 8; ++i)
#pragma unroll
      for (int j = 0; j < NH; ++j) {
        c0[j] += A0[i] * w[i][j];
        c1[j] += A1[i] * w[i][j];
      }
    float v0 = reduce16(c0, lane);
    float v1 = reduce16(c1, lane);
    if (lane < 16)      h0[(size_t)r0 * NH + lane] = v0;
    else if (lane < 32) h0[(size_t)(r0 + 1) * NH + (lane & 15)] = v1;
  }
}

// ---------------------------------------------------------------------------
// ebuf prefill with pad payload.
// ---------------------------------------------------------------------------
__global__ __launch_bounds__(256) void prefill_kernel(int4* __restrict__ ebuf4) {
  int i = blockIdx.x * blockDim.x + threadIdx.x;
  if (i < NEPAD / 4) ebuf4[i] = make_int4(PADVAL, PADVAL, PADVAL, PADVAL);
}

// ---------------------------------------------------------------------------
// Bucket histogram, int4-vectorized grid-stride.
// ---------------------------------------------------------------------------
__global__ __launch_bounds__(256) void bucket_hist_kernel(const int* __restrict__ ei,
                                                          int* __restrict__ gcount) {
  __shared__ int hist[NBUCK];
  for (int i = threadIdx.x; i < NBUCK; i += 256) hist[i] = 0;
  __syncthreads();
  const int4* d4 = (const int4*)(ei + NE);
  int stride = gridDim.x * 256;
  for (int i = blockIdx.x * 256 + threadIdx.x; i < NE / 4; i += stride) {
    int4 v = d4[i];
    atomicAdd(&hist[v.x >> 6], 1);
    atomicAdd(&hist[v.y >> 6], 1);
    atomicAdd(&hist[v.z >> 6], 1);
    atomicAdd(&hist[v.w >> 6], 1);
  }
  __syncthreads();
  for (int i = threadIdx.x; i < NBUCK; i += 256) {
    int c = hist[i];
    if (c) atomicAdd(&gcount[i], c);
  }
}

// ---------------------------------------------------------------------------
// Exclusive scan of PADDED bucket counts (single block, 1024 thr, 2/thread).
// ---------------------------------------------------------------------------
__global__ __launch_bounds__(1024) void bucket_scan_kernel(const int* __restrict__ gcount,
                                                           int* __restrict__ gbase,
                                                           int* __restrict__ gcursor) {
  __shared__ int s[1024];
  int t = threadIdx.x;
  int i0 = 2 * t, i1 = 2 * t + 1;
  int a0 = (i0 < NBUCK) ? ((gcount[i0] + ASTEP - 1) / ASTEP) * ASTEP : 0;
  int a1 = (i1 < NBUCK) ? ((gcount[i1] + ASTEP - 1) / ASTEP) * ASTEP : 0;
  s[t] = a0 + a1;
  __syncthreads();
  for (int off = 1; off < 1024; off <<= 1) {
    int v = (t >= off) ? s[t - off] : 0;
    __syncthreads();
    s[t] += v;
    __syncthreads();
  }
  int exclPair = s[t] - (a0 + a1);
  if (i0 < NBUCK) { gbase[i0] = exclPair;      gcursor[i0] = exclPair; }
  if (i1 < NBUCK) { gbase[i1] = exclPair + a0; gcursor[i1] = exclPair + a0; }
  if (t == 1023) gbase[NBUCK] = s[1023];
}

// ---------------------------------------------------------------------------
// Partition: chunked multi-split.  Payload: (local_dst << 17) | src.
// ---------------------------------------------------------------------------
__global__ __launch_bounds__(256) void partition_kernel(const int* __restrict__ ei,
                                                        int* __restrict__ gcursor,
                                                        int* __restrict__ ebuf) {
  __shared__ int hist[NBUCK];
  __shared__ int cbase[NBUCK];
  for (int i = threadIdx.x; i < NBUCK; i += 256) hist[i] = 0;
  __syncthreads();
  const int4* d4 = (const int4*)(ei + NE);
  const int4* s4 = (const int4*)ei;
  int stride = gridDim.x * 256;
  for (int i = blockIdx.x * 256 + threadIdx.x; i < NE / 4; i += stride) {
    int4 v = d4[i];
    atomicAdd(&hist[v.x >> 6], 1);
    atomicAdd(&hist[v.y >> 6], 1);
    atomicAdd(&hist[v.z >> 6], 1);
    atomicAdd(&hist[v.w >> 6], 1);
  }
  __syncthreads();
  for (int i = threadIdx.x; i < NBUCK; i += 256) {
    int c = hist[i];
    cbase[i] = c ? atomicAdd(&gcursor[i], c) : 0;
  }
  __syncthreads();
  for (int i = threadIdx.x; i < NBUCK; i += 256) hist[i] = 0;
  __syncthreads();
  for (int i = blockIdx.x * 256 + threadIdx.x; i < NE / 4; i += stride) {
    int4 d = d4[i];
    int4 s = s4[i];
    int b0 = d.x >> 6, b1 = d.y >> 6, b2 = d.z >> 6, b3 = d.w >> 6;
    int o0 = atomicAdd(&hist[b0], 1);
    int o1 = atomicAdd(&hist[b1], 1);
    int o2 = atomicAdd(&hist[b2], 1);
    int o3 = atomicAdd(&hist[b3], 1);
    ebuf[cbase[b0] + o0] = ((d.x & 63) << 17) | s.x;
    ebuf[cbase[b1] + o1] = ((d.y & 63) << 17) | s.y;
    ebuf[cbase[b2] + o2] = ((d.z & 63) << 17) | s.z;
    ebuf[cbase[b3] + o3] = ((d.w & 63) << 17) | s.w;
  }
}

// ---------------------------------------------------------------------------
// Layer-1 aggregate + relu + bias + W2.  One block per 64-node bucket.
// 4 lanes/edge (float4), 512 edges/iter.  sched_barrier(0) pins the
// 3-phase schedule: 8 idx loads | 8 gathers | 32 LDS atomics -> 8 gathers
// in flight per wave (the compiler refuses otherwise: R4/R5 VGPR=24..28).
// ---------------------------------------------------------------------------
__global__ __launch_bounds__(256) void agg1_kernel(const int* __restrict__ gbase,
                                                   const int* __restrict__ ebuf,
                                                   const float* __restrict__ h0,
                                                   const float* __restrict__ b1,
                                                   const float* __restrict__ W2,
                                                   float* __restrict__ p) {
  __shared__ float acc[BUCKSZ * 17];
  for (int i = threadIdx.x; i < BUCKSZ * 17; i += 256) acc[i] = 0.f;
  __syncthreads();
  int b = blockIdx.x;
  int start = gbase[b];
  int nIter = (gbase[b + 1] - start) >> 9;
  int eg = threadIdx.x >> 2, c = threadIdx.x & 3;
  const float* hc = h0 + 4 * c;
  for (int it = 0; it < nIter; ++it) {
    int e = start + it * 512 + eg;
    int pk[8];
#pragma unroll
    for (int u = 0; u < 8; ++u) pk[u] = ebuf[e + (u << 6)];
    SBAR();
    float4 hv[8];
#pragma unroll
    for (int u = 0; u < 8; ++u)
      hv[u] = *(const float4*)(hc + (size_t)(pk[u] & 0x1FFFF) * NH);
    SBAR();
#pragma unroll
    for (int u = 0; u < 8; ++u) {
      float* a = &acc[(pk[u] >> 17) * 17 + 4 * c];
      atomicAdd(a + 0, hv[u].x);
      atomicAdd(a + 1, hv[u].y);
      atomicAdd(a + 2, hv[u].z);
      atomicAdd(a + 3, hv[u].w);
    }
    SBAR();
  }
  __syncthreads();
  int li = threadIdx.x;
  if (li < BUCKSZ) {
    int node = b * BUCKSZ + li;
    if (node < NN) {
      float h[NH];
#pragma unroll
      for (int k = 0; k < NH; ++k) h[k] = fmaxf(acc[li * 17 + k] + b1[k], 0.f);
      float o[8];
#pragma unroll
      for (int j = 0; j < NC; ++j) {
        float s = 0.f;
#pragma unroll
        for (int k = 0; k < NH; ++k) s += h[k] * W2[k * NC + j];
        o[j] = s;
      }
      o[7] = 0.f;
      float4* pr = (float4*)(p + (size_t)node * 8);
      pr[0] = make_float4(o[0], o[1], o[2], o[3]);
      pr[1] = make_float4(o[4], o[5], o[6], o[7]);
    }
  }
}

// ---------------------------------------------------------------------------
// Layer-2 aggregate + bias + log_softmax.  4 lanes/edge (float2),
// 512 edges/iter, same pinned 3-phase schedule.  LDS acc 64 x 9.
// ---------------------------------------------------------------------------
__global__ __launch_bounds__(256) void agg2_kernel(const int* __restrict__ gbase,
                                                   const int* __restrict__ ebuf,
                                                   const float* __restrict__ p,
                                                   const float* __restrict__ b2,
                                                   float* __restrict__ out) {
  __shared__ float acc[BUCKSZ * 9];
  for (int i = threadIdx.x; i < BUCKSZ * 9; i += 256) acc[i] = 0.f;
  __syncthreads();
  int b = blockIdx.x;
  int start = gbase[b];
  int nIter = (gbase[b + 1] - start) >> 9;
  int eg = threadIdx.x >> 2, c = threadIdx.x & 3;
  const float* pc = p + 2 * c;
  for (int it = 0; it < nIter; ++it) {
    int e = start + it * 512 + eg;
    int pk[8];
#pragma unroll
    for (int u = 0; u < 8; ++u) pk[u] = ebuf[e + (u << 6)];
    SBAR();
    float2 pv[8];
#pragma unroll
    for (int u = 0; u < 8; ++u)
      pv[u] = *(const float2*)(pc + (size_t)(pk[u] & 0x1FFFF) * 8);
    SBAR();
#pragma unroll
    for (int u = 0; u < 8; ++u) {
      float* a = &acc[(pk[u] >> 17) * 9 + 2 * c];
      atomicAdd(a + 0, pv[u].x);
      atomicAdd(a + 1, pv[u].y);
    }
    SBAR();
  }
  __syncthreads();
  int li = threadIdx.x;
  if (li < BUCKSZ) {
    int node = b * BUCKSZ + li;
    if (node < NN) {
      float z[NC];
      float m = -1e30f;
#pragma unroll
      for (int j = 0; j < NC; ++j) {
        z[j] = acc[li * 9 + j] + b2[j];
        m = fmaxf(m, z[j]);
      }
      float s = 0.f;
#pragma unroll
      for (int j = 0; j < NC; ++j) s += __expf(z[j] - m);
      float l = __logf(s);
#pragma unroll
      for (int j = 0; j < NC; ++j) out[(size_t)node * NC + j] = z[j] - m - l;
    }
  }
}

extern "C" void kernel_launch(void* const* d_in, const int* in_sizes, int n_in,
                              void* d_out, int out_size, void* d_ws, size_t ws_size,
                              hipStream_t stream) {
  const float* x  = (const float*)d_in[0];
  const int*   ei = (const int*)d_in[1];
  const float* W1 = (const float*)d_in[2];
  const float* b1 = (const float*)d_in[3];
  const float* W2 = (const float*)d_in[4];
  const float* b2 = (const float*)d_in[5];
  float* out = (float*)d_out;

  // ws layout (~25.7 MB); h0 and p carry one extra ZERO pad row (index NN).
  float* h0      = (float*)d_ws;                        // (NN+1)*16
  float* p       = h0 + (size_t)(NN + 1) * NH;          // (NN+1)*8
  int*   ebuf    = (int*)(p + (size_t)(NN + 1) * 8);    // NEPAD
  int*   gcount  = ebuf + NEPAD;                        // NBUCK
  int*   gbase   = gcount + NBUCK;                      // NBUCK+1
  int*   gcursor = gbase + NBUCK + 1;                   // NBUCK

  hipMemsetAsync(gcount, 0, NBUCK * sizeof(int), stream);
  hipMemsetAsync(h0 + (size_t)NN * NH, 0, NH * sizeof(float), stream);
  hipMemsetAsync(p + (size_t)NN * 8, 0, 8 * sizeof(float), stream);

  prefill_kernel<<<(NEPAD / 4 + 255) / 256, 256, 0, stream>>>((int4*)ebuf);
  bucket_hist_kernel<<<256, 256, 0, stream>>>(ei, gcount);
  bucket_scan_kernel<<<1, 1024, 0, stream>>>(gcount, gbase, gcursor);
  partition_kernel<<<PBLK, 256, 0, stream>>>(ei, gcursor, ebuf);
  gemm1_kernel<<<2048, 256, 0, stream>>>(x, W1, h0);
  agg1_kernel<<<NBUCK, 256, 0, stream>>>(gbase, ebuf, h0, b1, W2, p);
  agg2_kernel<<<NBUCK, 256, 0, stream>>>(gbase, ebuf, p, b2, out);
}